// Round 16
// baseline (174.647 us; speedup 1.0000x reference)
//
#include <hip/hip_runtime.h>
#include <math.h>

#define BATCH 4
#define CH    256   // feature channels == depth of sampled volume
#define HH    128
#define WW    128
#define PC    256   // para channels
#define PI_F  3.14159f
#define PLANE (HH * WW)   // 16384 floats

// Padded LDS plane: rows -1..129 (index y+1 in [0,130]), cols -1..132.
// Stride 134 words (twice-VERIFIED geometry): 134 mod 32 = 6. Border +
// padding cells hold 0.0f: OOB sampling reads stored zeros =>
// padding_mode='zeros' with NO mask VALU. (PSTRIDE 133 failed warm-replay
// correctness in R14 — do not revisit.)
#define PSTRIDE 134
#define PROWS   131
#define BUFSZ   (PROWS * PSTRIDE)   // 17554 words = 70216 B
#define NBORDER 1170                // BUFSZ - 128*128 interior words

// Light barrier: drains LDS ops only (lgkmcnt), NOT vmcnt — global staging
// loads stay in flight across the entire params phase.
__device__ __forceinline__ void barrier_lds() {
    asm volatile("s_waitcnt lgkmcnt(0)\n\ts_barrier" ::: "memory");
}

struct Stage { float4 a[4]; float4 b[4]; };

__device__ __forceinline__ Stage stage_load(const float* __restrict__ pl0,
                                            const float* __restrict__ pl1, int t) {
    Stage s;
#pragma unroll
    for (int j = 0; j < 4; ++j) {
        const int f = 4 * (t + 1024 * j);
        s.a[j] = *(const float4*)(pl0 + f);
        s.b[j] = *(const float4*)(pl1 + f);
    }
    return s;
}

// z-combine + scatter into padded layout (interior cells only; border cells
// remain zero). 4 consecutive floats -> compiler merges to ds_write2_b32.
__device__ __forceinline__ void stage_store_pad(float* __restrict__ buf, const Stage& s,
                                                float wz0, float wz1, int t) {
#pragma unroll
    for (int j = 0; j < 4; ++j) {
        const int f = 4 * (t + 1024 * j);
        const int y = f >> 7, x = f & (WW - 1);
        float* p = &buf[(y + 1) * PSTRIDE + (x + 1)];
        p[0] = fmaf(wz0, s.a[j].x, wz1 * s.b[j].x);
        p[1] = fmaf(wz0, s.a[j].y, wz1 * s.b[j].y);
        p[2] = fmaf(wz0, s.a[j].z, wz1 * s.b[j].z);
        p[3] = fmaf(wz0, s.a[j].w, wz1 * s.b[j].w);
    }
}

// ---------------------------------------------------------------------------
// SINGLE-LAUNCH fused kernel: 1024 blocks x 1024 threads, one plane/block,
// single padded LDS plane (75.4 KiB total LDS) => 2 blocks/CU, 32 waves/CU.
//
// Per-block params (replaces the ~12 us params dispatch): each block
// recomputes p = relu(pc@W1+b1) (64 MACs/thread from L2-resident W1, hidden
// under the plane staging-load flight — barriers are lgkmcnt-only) and ONLY
// its own channel's 4 head dots (1 MAC x 4/lane on 4 waves + shfl reduce;
// the 4 weight scalars/thread are issued BEFORE the stage burst so their
// vmcnt wait is zero). t0's transcendentals overlap the scatter drain.
//
// Pipeline: hw-prefetch -> stage loads -> GEMV -> bar -> p_sh -> bar ->
// head-dot -> bar -> [t0 transcendentals || border-zero + scatter] -> bar ->
// gather -> coalesced store.
// ---------------------------------------------------------------------------
__global__ __launch_bounds__(1024, 8)
void adaat_fused_kernel(const float* __restrict__ fm,
                        const float* __restrict__ pc,
                        const float* __restrict__ W1, const float* __restrict__ b1,
                        const float* __restrict__ Ws, const float* __restrict__ bs,
                        const float* __restrict__ Wr, const float* __restrict__ br,
                        const float* __restrict__ Wt, const float* __restrict__ bt,
                        float* __restrict__ out) {
    __shared__ float  lds[BUFSZ];   // 70.2 KiB padded plane
    __shared__ float  red[1024];    // GEMV reduce scratch (4 KiB)
    __shared__ float  p_sh[PC];     // 1 KiB
    __shared__ float  sh_head[4];
    __shared__ float4 sh_par;

    const int t  = threadIdx.x;
    const int wv = t >> 6, l = t & 63;

    // XCD-chunked swizzle (grid 1024 = 8 XCDs x 128, bijective): each XCD
    // owns a contiguous channel range -> adjacent channels share a source
    // plane in the same per-XCD L2 (FETCH 65->37 MB measured in R1).
    const int bid = blockIdx.x;
    const int lc  = ((bid & 7) << 7) | (bid >> 3);   // logical (batch,channel)
    const int b   = lc >> 8;
    const int c   = lc & (CH - 1);

    // ---- 0) head-dot weight prefetch: FIRST loads issued, so the head-dot
    //         phase's vmcnt wait is ~zero (they land before the stage burst).
    //         wave wv<4 owns head wv for this block's channel c. ----
    float hw[4];
    if (wv < 4) {
        const float* wp; int stride;
        if      (wv == 0) { wp = Ws + c;                stride = PC;     }
        else if (wv == 1) { wp = Wr + c;                stride = PC;     }
        else              { wp = Wt + 2 * c + (wv == 3); stride = 2 * PC; }
#pragma unroll
        for (int m = 0; m < 4; ++m)
            hw[m] = wp[(size_t)(l + 64 * m) * stride];
    }
    // t0's bias scalars, issued early too
    float b_s = 0.f, b_r = 0.f, b_t0 = 0.f, b_t1 = 0.f;
    if (t == 0) {
        b_s = bs[c]; b_r = br[c]; b_t0 = bt[2 * c]; b_t1 = bt[2 * c + 1];
    }

    // block-uniform staging constants (scalarized)
    const float* base = fm + (size_t)b * (CH * PLANE);
    const float  iz = (256.0f / 255.0f) * (float)c - 0.5f;
    const float  zf = floorf(iz);
    const float  fz = iz - zf;
    const int    z0 = (int)zf;
    const float  w0 = (z0 >= 0)     ? (1.0f - fz) : 0.0f;
    const float  w1 = (z0 + 1 < CH) ? fz          : 0.0f;
    const float* pl0 = base + (size_t)max(z0, 0)          * PLANE;
    const float* pl1 = base + (size_t)min(z0 + 1, CH - 1) * PLANE;

    // ---- 1) plane staging loads: issued now, in flight through params ----
    Stage s = stage_load(pl0, pl1, t);

    // ---- 2) GEMV p = relu(pc@W1+b1), 4-way k-split (verified rounding);
    //         W1 is L2-resident (read by all 1024 blocks). Runs entirely
    //         under the staging-load flight. ----
    {
        const int jj = t & 255, kk = t >> 8;
        const float* pcb = pc + b * PC + kk * 64;
        const float* w   = W1 + (kk * 64) * PC + jj;
        float acc = 0.0f;
#pragma unroll 8
        for (int i = 0; i < 64; ++i)
            acc = fmaf(pcb[i], w[i * PC], acc);
        red[t] = acc;
    }
    barrier_lds();
    if (t < 256)
        p_sh[t] = fmaxf(red[t] + red[256 + t] + red[512 + t] + red[768 + t] + b1[t], 0.0f);
    barrier_lds();

    // ---- 3) head dots: wave wv<4, lane l: k = l+64m; shfl-tree reduce ----
    if (wv < 4) {
        float dot = 0.0f;
#pragma unroll
        for (int m = 0; m < 4; ++m)
            dot = fmaf(p_sh[l + 64 * m], hw[m], dot);
#pragma unroll
        for (int off = 32; off >= 1; off >>= 1)
            dot += __shfl_xor(dot, off, 64);
        if (l == 0) sh_head[wv] = dot;
    }
    barrier_lds();   // sh_head visible

    // ---- 4) t0 transcendentals, OVERLAPPED with border-zero + scatter
    //         (t0's ~400 cyc hides under the other waves' vmcnt drain) ----
    if (t == 0) {
        const float s2  = 2.0f / (1.0f + expf(-(sh_head[0] + b_s)));
        const float ang = tanhf(sh_head[1] + b_r) * PI_F;
        float sa, ca;
        sincosf(ang, &sa, &ca);
        const float A  = s2 * ca, B = s2 * sa;
        const float Tx = tanhf(sh_head[2] + b_t0);
        const float Ty = tanhf(sh_head[3] + b_t1);
        sh_par = make_float4(A * (128.0f / 127.0f),
                             B * (128.0f / 127.0f),
                             64.0f * (Tx - A + B) + 64.5f,   // +1 border bias
                             64.0f * (Ty - A - B) + 64.5f);
    }

    // border zero (1170 words; interior fully overwritten by scatter)
#pragma unroll
    for (int i = t; i < NBORDER; i += 1024) {
        int row, col;
        if (i < 402) {
            row = i / 134;
            if (row == 1) row = 129; else if (row == 2) row = 130;
            col = i % 134;
        } else {
            const int j = i - 402;
            row = 1 + j / 6;
            const int cs = j % 6;
            col = (cs == 0) ? 0 : 128 + cs;
        }
        lds[row * PSTRIDE + col] = 0.0f;
    }

    // z-combine + scatter (each wave waits only its own vmcnt)
    stage_store_pad(lds, s, w0, w1, t);

    barrier_lds();   // plane + sh_par visible; gather may start

    // ---- 5) gather: wave wv owns rows [8wv, 8wv+8), lane = column ----
    // 64 lanes store 64 consecutive dwords (256 B / instr). Clamp coord into
    // [0, 129.99]: far-OOB pixels land entirely on zero cells; edge pixels
    // get the exact zero-padded bilinear weights.
    {
        const float4 P  = sh_par;
        const float  cA = P.x, cB = P.y;
        float* outp = out + (size_t)lc * PLANE;
        const float xf0 = (float)l;
        float rowf = (float)(wv * 8);
#pragma unroll 2
        for (int r = 0; r < 8; ++r) {
            const float bx = fmaf(-cB, rowf, P.z);   // per-row partials
            const float by = fmaf( cA, rowf, P.w);
            float* orow = outp + (wv * 8 + r) * WW;
#pragma unroll
            for (int h = 0; h < 2; ++h) {
                const float xf  = xf0 + 64.0f * h;
                const float ix  = fmaf(cA, xf, bx);
                const float iy  = fmaf(cB, xf, by);
                const float xc  = fminf(fmaxf(ix, 0.0f), 129.99f);
                const float yc  = fminf(fmaxf(iy, 0.0f), 129.99f);
                const float x0f = floorf(xc), y0f = floorf(yc);
                const float fx  = xc - x0f,   fy  = yc - y0f;
                const int   a   = (int)y0f * PSTRIDE + (int)x0f;
                const float v00 = lds[a],           v01 = lds[a + 1];           // ds_read2
                const float v10 = lds[a + PSTRIDE], v11 = lds[a + PSTRIDE + 1]; // ds_read2
                const float h0  = fmaf(fx, v01 - v00, v00);
                const float h1  = fmaf(fx, v11 - v10, v10);
                orow[h * 64 + l] = fmaf(fy, h1 - h0, h0);
            }
            rowf += 1.0f;
        }
    }
}

// ---------------------------------------------------------------------------
extern "C" void kernel_launch(void* const* d_in, const int* in_sizes, int n_in,
                              void* d_out, int out_size, void* d_ws, size_t ws_size,
                              hipStream_t stream) {
    const float* feature_map = (const float*)d_in[0];  // [4,256,128,128]
    const float* para_code   = (const float*)d_in[1];  // [4,256]
    const float* W1 = (const float*)d_in[2];
    const float* b1 = (const float*)d_in[3];
    const float* Ws = (const float*)d_in[4];
    const float* bs = (const float*)d_in[5];
    const float* Wr = (const float*)d_in[6];
    const float* br = (const float*)d_in[7];
    const float* Wt = (const float*)d_in[8];
    const float* bt = (const float*)d_in[9];

    adaat_fused_kernel<<<BATCH * CH, 1024, 0, stream>>>(
        feature_map, para_code, W1, b1, Ws, bs, Wr, br, Wt, bt, (float*)d_out);
}

// Round 19
// 148.264 us; speedup vs baseline: 1.1779x; 1.1779x over previous
//
#include <hip/hip_runtime.h>
#include <math.h>

#define BATCH 4
#define CH    256   // feature channels == depth of sampled volume
#define HH    128
#define WW    128
#define PC    256   // para channels
#define PI_F  3.14159f
#define PLANE (HH * WW)   // 16384 floats

// Padded LDS plane: rows -1..129 (index y+1 in [0,130]), cols -1..132.
// Stride 134 words (twice-VERIFIED geometry). Border + padding cells hold
// 0.0f: OOB sampling reads stored zeros => padding_mode='zeros' with NO mask
// VALU. (PSTRIDE 133 failed warm-replay correctness in R14 — do not revisit.)
#define PSTRIDE 134
#define PROWS   131
#define BUFSZ   (PROWS * PSTRIDE)   // 17554 words = 70216 B
#define NBORDER 1170                // BUFSZ - 128*128 interior words

// Workspace layout (floats): [1024,2048) hd_s; [2048,3072) hd_r;
// [3072,5120) ht (b*512 + col). Total 20 KiB.
#define WS_S    1024
#define WS_R    2048
#define WS_T    3072

// Light barrier: drains LDS ops only (lgkmcnt), NOT vmcnt.
__device__ __forceinline__ void barrier_lds() {
    asm volatile("s_waitcnt lgkmcnt(0)\n\ts_barrier" ::: "memory");
}

struct Stage { float4 a[4]; float4 b[4]; };

__device__ __forceinline__ Stage stage_load(const float* __restrict__ pl0,
                                            const float* __restrict__ pl1, int t) {
    Stage s;
#pragma unroll
    for (int j = 0; j < 4; ++j) {
        const int f = 4 * (t + 1024 * j);
        s.a[j] = *(const float4*)(pl0 + f);
        s.b[j] = *(const float4*)(pl1 + f);
    }
    return s;
}

// z-combine + scatter into padded layout (interior cells only; border cells
// remain zero). 4 consecutive floats -> compiler merges to ds_write2_b32.
__device__ __forceinline__ void stage_store_pad(float* __restrict__ buf, const Stage& s,
                                                float wz0, float wz1, int t) {
#pragma unroll
    for (int j = 0; j < 4; ++j) {
        const int f = 4 * (t + 1024 * j);
        const int y = f >> 7, x = f & (WW - 1);
        float* p = &buf[(y + 1) * PSTRIDE + (x + 1)];
        p[0] = fmaf(wz0, s.a[j].x, wz1 * s.b[j].x);
        p[1] = fmaf(wz0, s.a[j].y, wz1 * s.b[j].y);
        p[2] = fmaf(wz0, s.a[j].z, wz1 * s.b[j].z);
        p[3] = fmaf(wz0, s.a[j].w, wz1 * s.b[j].w);
    }
}

// ---------------------------------------------------------------------------
// Merged params kernel (VERIFIED R15): 16 blocks x 1024 threads, block =
// (batch b, group g). Phase-B weights prefetched to registers before phase A
// (GEMV into LDS), head dots from registers, raw dots to workspace.
// NOTE (R16 lesson): do NOT fold this into the main kernel — the strided W1
// GEMV costs ~4 MB of L2 traffic per block; x1024 blocks = L2-BW-bound +35us.
// ---------------------------------------------------------------------------
__global__ __launch_bounds__(1024)
void adaat_params_kernel(const float* __restrict__ pc,
                         const float* __restrict__ W1, const float* __restrict__ b1,
                         const float* __restrict__ Ws,
                         const float* __restrict__ Wr,
                         const float* __restrict__ Wt,
                         float* __restrict__ ws) {
    __shared__ float red[1024];
    __shared__ float p_sh[PC];
    const int t = threadIdx.x;
    const int b = blockIdx.x >> 2;
    const int g = blockIdx.x & 3;
    const int o = t & 255, kk = t >> 8;

    // ---- phase-B weight prefetch (independent of p; issued first) ----
    const float* wp; int stride; int dst;
    if      (g == 0) { wp = Ws + o;       stride = PC;     dst = WS_S + b * 256 + o;       }
    else if (g == 1) { wp = Wr + o;       stride = PC;     dst = WS_R + b * 256 + o;       }
    else if (g == 2) { wp = Wt + o;       stride = 2 * PC; dst = WS_T + b * 512 + o;       }
    else             { wp = Wt + 256 + o; stride = 2 * PC; dst = WS_T + b * 512 + 256 + o; }
    float wb[64];
    {
        const float* wkB = wp + (size_t)(kk * 64) * stride;
#pragma unroll
        for (int i = 0; i < 64; ++i)
            wb[i] = wkB[(size_t)i * stride];
    }

    // ---- phase A: p = relu(pc @ W1 + b1), 4-way k-split (P1 rounding) ----
    {
        const float* pcb = pc + b * PC + kk * 64;
        const float* w   = W1 + (kk * 64) * PC + o;
        float acc = 0.0f;
#pragma unroll 8
        for (int i = 0; i < 64; ++i)
            acc = fmaf(pcb[i], w[i * PC], acc);
        red[t] = acc;
    }
    __syncthreads();
    if (t < 256)
        p_sh[t] = fmaxf(red[t] + red[256 + t] + red[512 + t] + red[768 + t] + b1[t], 0.0f);
    __syncthreads();

    // ---- phase B: head dots from prefetched registers (P2 rounding) ----
    {
        const float* pk = p_sh + kk * 64;
        float acc = 0.0f;
#pragma unroll
        for (int i = 0; i < 64; ++i)
            acc = fmaf(pk[i], wb[i], acc);
        red[t] = acc;
    }
    __syncthreads();
    if (t < 256)
        ws[dst] = red[t] + red[256 + t] + red[512 + t] + red[768 + t];
}

// ---------------------------------------------------------------------------
// Main kernel: 1024 blocks x 1024 threads, one plane per block, single padded
// LDS buffer (70.2 KiB) => 2 blocks/CU, 32 waves/CU.
// R17 deltas vs verified R15: (1) t0's ws/bias loads issued BEFORE the stage
// burst (in-order vmcnt: transcendentals now overlap the staging flight
// instead of serializing after it); (2) v_med3 clamps; (3) lane covers
// x=2l,2l+1 -> one dwordx2 store per row (half the store instrs), per-pixel
// fmaf chains unchanged (identical rounding).
// ---------------------------------------------------------------------------
__global__ __launch_bounds__(1024, 8)
void adaat_fused_kernel(const float* __restrict__ fm,
                        const float* __restrict__ ws,
                        const float* __restrict__ bs,
                        const float* __restrict__ br,
                        const float* __restrict__ bt,
                        float* __restrict__ out) {
    __shared__ float  lds[BUFSZ];   // 70.2 KiB single padded plane
    __shared__ float4 sh_par;

    const int t = threadIdx.x;

    // XCD-chunked swizzle (grid 1024 = 8 XCDs x 128, bijective): each XCD
    // owns a contiguous channel range -> adjacent channels share a source
    // plane in the same per-XCD L2 (FETCH 65->37 MB measured in R1).
    const int bid = blockIdx.x;
    const int lc  = ((bid & 7) << 7) | (bid >> 3);   // logical (batch,channel)
    const int b   = lc >> 8;
    const int c   = lc & (CH - 1);

    // ---- 0) t0 scalar loads FIRST: they sit ahead of the stage burst in
    //         the in-order vmcnt queue, so the transcendentals can run while
    //         the plane loads are still in flight. ----
    float ds = 0.f, dr = 0.f, dt0 = 0.f, dt1 = 0.f;
    float b_s = 0.f, b_r = 0.f, b_t0 = 0.f, b_t1 = 0.f;
    if (t == 0) {
        ds  = ws[WS_S + lc];
        dr  = ws[WS_R + lc];
        dt0 = ws[WS_T + b * 512 + 2 * c];
        dt1 = ws[WS_T + b * 512 + 2 * c + 1];
        b_s = bs[c]; b_r = br[c]; b_t0 = bt[2 * c]; b_t1 = bt[2 * c + 1];
    }

    // block-uniform staging constants (scalarized)
    const float* base = fm + (size_t)b * (CH * PLANE);
    const float  iz = (256.0f / 255.0f) * (float)c - 0.5f;
    const float  zf = floorf(iz);
    const float  fz = iz - zf;
    const int    z0 = (int)zf;
    const float  w0 = (z0 >= 0)     ? (1.0f - fz) : 0.0f;
    const float  w1 = (z0 + 1 < CH) ? fz          : 0.0f;
    const float* pl0 = base + (size_t)max(z0, 0)          * PLANE;
    const float* pl1 = base + (size_t)min(z0 + 1, CH - 1) * PLANE;

    // ---- 1) plane staging loads issued, stay in flight ----
    Stage s = stage_load(pl0, pl1, t);

    // ---- 2) t0 transcendentals (overlap the staging flight) ----
    if (t == 0) {
        const float s2  = 2.0f / (1.0f + expf(-(ds + b_s)));
        const float ang = tanhf(dr + b_r) * PI_F;
        float sa, ca;
        sincosf(ang, &sa, &ca);
        const float A  = s2 * ca, B = s2 * sa;
        const float Tx = tanhf(dt0 + b_t0);
        const float Ty = tanhf(dt1 + b_t1);
        sh_par = make_float4(A * (128.0f / 127.0f),
                             B * (128.0f / 127.0f),
                             64.0f * (Tx - A + B) + 64.5f,   // +1 border bias
                             64.0f * (Ty - A - B) + 64.5f);
    }

    // ---- 3) zero ONLY the border cells (1170 words; interior is fully
    //         overwritten by stage_store_pad). ----
#pragma unroll
    for (int i = t; i < NBORDER; i += 1024) {
        int row, col;
        if (i < 402) {
            row = i / 134;
            if (row == 1) row = 129; else if (row == 2) row = 130;
            col = i % 134;
        } else {
            const int j = i - 402;
            row = 1 + j / 6;
            const int cs = j % 6;
            col = (cs == 0) ? 0 : 128 + cs;
        }
        lds[row * PSTRIDE + col] = 0.0f;
    }

    // ---- 4) z-combine + scatter (waits only its own vmcnt) ----
    stage_store_pad(lds, s, w0, w1, t);

    barrier_lds();   // plane + sh_par visible; the ONLY barrier

    // ---- 5) gather: wave wv owns rows [8wv, 8wv+8); lane l covers
    //         x = 2l and 2l+1 -> ONE dwordx2 store per row (512 B / wave
    //         instr). Per-pixel fmaf chains identical to the verified R15.
    //         Clamp via v_med3 (single VALU op). ----
    {
        const int    wv = t >> 6, l = t & 63;
        const float4 P  = sh_par;
        const float  cA = P.x, cB = P.y;
        float* outp = out + (size_t)lc * PLANE;
        const float xf0 = (float)(2 * l);
        const float xf1 = (float)(2 * l + 1);
        float rowf = (float)(wv * 8);
#pragma unroll 2
        for (int r = 0; r < 8; ++r) {
            const float bx = fmaf(-cB, rowf, P.z);   // per-row partials
            const float by = fmaf( cA, rowf, P.w);
            float* orow = outp + (wv * 8 + r) * WW;
            float v[2];
#pragma unroll
            for (int h = 0; h < 2; ++h) {
                const float xf  = (h == 0) ? xf0 : xf1;
                const float ix  = fmaf(cA, xf, bx);
                const float iy  = fmaf(cB, xf, by);
                const float xc  = __builtin_amdgcn_fmed3f(ix, 0.0f, 129.99f);
                const float yc  = __builtin_amdgcn_fmed3f(iy, 0.0f, 129.99f);
                const float x0f = floorf(xc), y0f = floorf(yc);
                const float fx  = xc - x0f,   fy  = yc - y0f;
                const int   a   = (int)y0f * PSTRIDE + (int)x0f;
                const float v00 = lds[a],           v01 = lds[a + 1];           // ds_read2
                const float v10 = lds[a + PSTRIDE], v11 = lds[a + PSTRIDE + 1]; // ds_read2
                const float h0  = fmaf(fx, v01 - v00, v00);
                const float h1  = fmaf(fx, v11 - v10, v10);
                v[h] = fmaf(fy, h1 - h0, h0);
            }
            *(float2*)(orow + 2 * l) = make_float2(v[0], v[1]);   // dwordx2
            rowf += 1.0f;
        }
    }
}

// ---------------------------------------------------------------------------
extern "C" void kernel_launch(void* const* d_in, const int* in_sizes, int n_in,
                              void* d_out, int out_size, void* d_ws, size_t ws_size,
                              hipStream_t stream) {
    const float* feature_map = (const float*)d_in[0];  // [4,256,128,128]
    const float* para_code   = (const float*)d_in[1];  // [4,256]
    const float* W1 = (const float*)d_in[2];
    const float* b1 = (const float*)d_in[3];
    const float* Ws = (const float*)d_in[4];
    const float* bs = (const float*)d_in[5];
    const float* Wr = (const float*)d_in[6];
    const float* br = (const float*)d_in[7];
    const float* Wt = (const float*)d_in[8];
    const float* bt = (const float*)d_in[9];

    float* ws = (float*)d_ws;   // 5120 floats = 20 KiB

    adaat_params_kernel<<<4 * BATCH, 1024, 0, stream>>>(
        para_code, W1, b1, Ws, Wr, Wt, ws);
    adaat_fused_kernel<<<BATCH * CH, 1024, 0, stream>>>(
        feature_map, ws, bs, br, bt, (float*)d_out);
}